// Round 1
// baseline (244.911 us; speedup 1.0000x reference)
//
#include <hip/hip_runtime.h>

#define NTOK 197
#define NH 12
#define HD 64
#define DIMC 768
#define BATCH 64
#define ROWS (BATCH*NTOK)   // 12608
#define NPAD 224            // padded token count for Vt / P (7*32)
#define BHN (BATCH*NH)      // 768

typedef float f4 __attribute__((ext_vector_type(4)));
typedef __bf16 b8 __attribute__((ext_vector_type(8)));
typedef unsigned short u16x8 __attribute__((ext_vector_type(8)));
typedef unsigned short u16x4 __attribute__((ext_vector_type(4)));

__device__ inline unsigned short f2bf(float f) {
  unsigned u = __builtin_bit_cast(unsigned, f);
  u += 0x7fffu + ((u >> 16) & 1u);
  return (unsigned short)(u >> 16);
}

__device__ inline b8 ld8(const unsigned short* p) {
  return __builtin_bit_cast(b8, *(const u16x8*)p);
}

__device__ inline f4 mfma_bf16(b8 a, b8 b, f4 c) {
  return __builtin_amdgcn_mfma_f32_16x16x32_bf16(a, b, c, 0, 0, 0);
}

// ---------------- prep kernels ----------------

__global__ void k_cvt(const float* __restrict__ s, unsigned short* __restrict__ d, int n4) {
  int i = blockIdx.x * 256 + threadIdx.x;
  if (i < n4) {
    f4 v = *(const f4*)&s[(size_t)i * 4];
    u16x4 o = { f2bf(v[0]), f2bf(v[1]), f2bf(v[2]), f2bf(v[3]) };
    *(u16x4*)&d[(size_t)i * 4] = o;
  }
}

__global__ void k_bias(const float* __restrict__ table, const int* __restrict__ idx,
                       float* __restrict__ Bias) {
  int i = blockIdx.x * 256 + threadIdx.x;
  if (i < NH * NTOK * NTOK) {
    int h = i / (NTOK * NTOK);
    int nm = i - h * (NTOK * NTOK);
    Bias[i] = table[idx[nm] * NH + h];
  }
}

__global__ void k_vtpad(unsigned short* __restrict__ Vt) {
  int i = blockIdx.x * 256 + threadIdx.x;   // BHN*HD rows, pad cols 197..223
  const int PADW = NPAD - NTOK;             // 27
  if (i < BHN * HD * PADW) {
    int row = i / PADW, c = i - row * PADW;
    Vt[(size_t)row * NPAD + NTOK + c] = 0;
  }
}

// ---------------- GEMM (A[M][768] bf16 row-major, Bm[N][768] bf16 row-major = B^T) ----------------
// MODE 0: qkv epilogue -> Q,K,Vt scatter.  MODE 1: proj epilogue -> fp32 out + bias.

template<int MODE>
__global__ __launch_bounds__(256) void k_gemm(
    const unsigned short* __restrict__ A, const unsigned short* __restrict__ Bm,
    const float* __restrict__ bias0, const float* __restrict__ bias1,
    unsigned short* __restrict__ Qo, unsigned short* __restrict__ Ko,
    unsigned short* __restrict__ Vto, float* __restrict__ Co)
{
  __shared__ unsigned short As[128 * 32];
  __shared__ unsigned short Bs[128 * 32];
  int tid = threadIdx.x;
  int l = tid & 63, w = tid >> 6;
  int lr = l & 15, lg = l >> 4;
  int wr = w >> 1, wc = w & 1;
  int brow = blockIdx.x * 128, bcol = blockIdx.y * 128;

  f4 acc[4][4];
  #pragma unroll
  for (int i = 0; i < 4; i++)
    #pragma unroll
    for (int j = 0; j < 4; j++) acc[i][j] = (f4){0.f, 0.f, 0.f, 0.f};

  u16x8 va[2], vb[2];
  auto prefetch = [&](int k0) {
    #pragma unroll
    for (int i = 0; i < 2; i++) {
      int s = tid + i * 256;
      int row = s >> 2, ch = s & 3;
      int ra = brow + row; if (ra > ROWS - 1) ra = ROWS - 1;
      va[i] = *(const u16x8*)&A[(size_t)ra * DIMC + k0 + ch * 8];
      vb[i] = *(const u16x8*)&Bm[(size_t)(bcol + row) * DIMC + k0 + ch * 8];
    }
  };

  prefetch(0);
  for (int kt = 0; kt < DIMC / 32; kt++) {
    __syncthreads();
    #pragma unroll
    for (int i = 0; i < 2; i++) {
      int s = tid + i * 256;
      *(u16x8*)&As[s * 8] = va[i];
      *(u16x8*)&Bs[s * 8] = vb[i];
    }
    __syncthreads();
    if (kt < DIMC / 32 - 1) prefetch((kt + 1) * 32);

    b8 af[4], bfr[4];
    #pragma unroll
    for (int mi = 0; mi < 4; mi++) af[mi] = ld8(&As[(wr * 64 + mi * 16 + lr) * 32 + lg * 8]);
    #pragma unroll
    for (int ni = 0; ni < 4; ni++) bfr[ni] = ld8(&Bs[(wc * 64 + ni * 16 + lr) * 32 + lg * 8]);
    #pragma unroll
    for (int mi = 0; mi < 4; mi++)
      #pragma unroll
      for (int ni = 0; ni < 4; ni++)
        acc[mi][ni] = mfma_bf16(af[mi], bfr[ni], acc[mi][ni]);
  }

  #pragma unroll
  for (int mi = 0; mi < 4; mi++) {
    #pragma unroll
    for (int ni = 0; ni < 4; ni++) {
      #pragma unroll
      for (int r = 0; r < 4; r++) {
        int rg = brow + wr * 64 + mi * 16 + lg * 4 + r;
        int cg = bcol + wc * 64 + ni * 16 + lr;
        if (rg < ROWS) {
          float v = acc[mi][ni][r];
          if (MODE == 0) {
            int which = cg / DIMC;        // 0=q 1=k 2=v
            int rem = cg - which * DIMC;
            int h = rem >> 6, d = rem & 63;
            int b = rg / NTOK, n = rg - (rg / NTOK) * NTOK;
            int bh = b * NH + h;
            if (which == 0)      Qo[((size_t)bh * NTOK + n) * HD + d] = f2bf((v + bias0[rem]) * 0.125f);
            else if (which == 1) Ko[((size_t)bh * NTOK + n) * HD + d] = f2bf(v);
            else                 Vto[((size_t)bh * HD + d) * NPAD + n] = f2bf(v + bias1[rem]);
          } else {
            Co[(size_t)rg * DIMC + cg] = v + bias0[cg];
          }
        }
      }
    }
  }
}

// ---------------- fused attention: 1 block per (b,h), 4 waves ----------------

__global__ __launch_bounds__(256) void k_attn(
    const unsigned short* __restrict__ Q, const unsigned short* __restrict__ Kb,
    const unsigned short* __restrict__ Vt, const float* __restrict__ Bias,
    unsigned short* __restrict__ Abuf)
{
  int bh = blockIdx.x;
  int b = bh / NH, h = bh - (bh / NH) * NH;
  const unsigned short* q  = Q  + (size_t)bh * NTOK * HD;
  const unsigned short* kk = Kb + (size_t)bh * NTOK * HD;
  const unsigned short* vt = Vt + (size_t)bh * HD * NPAD;
  const float* bias = Bias + (size_t)h * NTOK * NTOK;

  __shared__ unsigned short P[4][16 * NPAD];

  int tid = threadIdx.x, w = tid >> 6, l = tid & 63;
  int lr = l & 15, lg = l >> 4;

  for (int mt = w; mt < 13; mt += 4) {
    int qrow = mt * 16 + lr; if (qrow > NTOK - 1) qrow = NTOK - 1;
    b8 qa0 = ld8(&q[qrow * HD + lg * 8]);
    b8 qa1 = ld8(&q[qrow * HD + 32 + lg * 8]);

    f4 s[13];
    #pragma unroll
    for (int jt = 0; jt < 13; jt++) {
      int krow = jt * 16 + lr; if (krow > NTOK - 1) krow = NTOK - 1;
      b8 kb0 = ld8(&kk[krow * HD + lg * 8]);
      b8 kb1 = ld8(&kk[krow * HD + 32 + lg * 8]);
      f4 a = (f4){0.f, 0.f, 0.f, 0.f};
      a = mfma_bf16(qa0, kb0, a);
      a = mfma_bf16(qa1, kb1, a);
      s[jt] = a;
    }

    // softmax over rows n = mt*16 + 4*lg + r (cols live across lr lanes x 13 tiles)
    #pragma unroll
    for (int r = 0; r < 4; r++) {
      int n = mt * 16 + 4 * lg + r;
      int nc = n > NTOK - 1 ? NTOK - 1 : n;
      float rm = -1e30f;
      #pragma unroll
      for (int jt = 0; jt < 13; jt++) {
        int m = jt * 16 + lr;
        float v = s[jt][r];
        v = (m < NTOK) ? (v + bias[nc * NTOK + m]) : -1e30f;
        s[jt][r] = v;
        rm = fmaxf(rm, v);
      }
      rm = fmaxf(rm, __shfl_xor(rm, 1));
      rm = fmaxf(rm, __shfl_xor(rm, 2));
      rm = fmaxf(rm, __shfl_xor(rm, 4));
      rm = fmaxf(rm, __shfl_xor(rm, 8));
      float sum = 0.f;
      #pragma unroll
      for (int jt = 0; jt < 13; jt++) {
        float p = __expf(s[jt][r] - rm);
        s[jt][r] = p;
        sum += p;
      }
      sum += __shfl_xor(sum, 1);
      sum += __shfl_xor(sum, 2);
      sum += __shfl_xor(sum, 4);
      sum += __shfl_xor(sum, 8);
      float inv = 1.0f / sum;
      #pragma unroll
      for (int jt = 0; jt < 13; jt++)
        P[w][(4 * lg + r) * NPAD + jt * 16 + lr] = f2bf(s[jt][r] * inv);
    }
    // zero pad cols 208..223 (cols 197..207 already written as 0 by the mask)
    #pragma unroll
    for (int e = 0; e < 4; e++) P[w][lr * NPAD + 208 + lg * 4 + e] = 0;

    __builtin_amdgcn_wave_barrier();

    // PV: O[16][64] = P[16][224] * V[224][64]  (V read as Vt[d][n])
    #pragma unroll
    for (int dt = 0; dt < 4; dt++) {
      f4 o = (f4){0.f, 0.f, 0.f, 0.f};
      #pragma unroll
      for (int ktk = 0; ktk < 7; ktk++) {
        b8 pa = ld8(&P[w][lr * NPAD + ktk * 32 + lg * 8]);
        b8 vb = ld8(&vt[(dt * 16 + lr) * NPAD + ktk * 32 + lg * 8]);
        o = mfma_bf16(pa, vb, o);
      }
      #pragma unroll
      for (int r = 0; r < 4; r++) {
        int n = mt * 16 + 4 * lg + r;
        if (n < NTOK)
          Abuf[((size_t)b * NTOK + n) * DIMC + h * HD + dt * 16 + lr] = f2bf(o[r]);
      }
    }
  }
}

// ---------------- launch ----------------

extern "C" void kernel_launch(void* const* d_in, const int* in_sizes, int n_in,
                              void* d_out, int out_size, void* d_ws, size_t ws_size,
                              hipStream_t stream) {
  const float* x      = (const float*)d_in[0];
  const float* qkv_w  = (const float*)d_in[1];
  const float* q_bias = (const float*)d_in[2];
  const float* v_bias = (const float*)d_in[3];
  const float* rtab   = (const float*)d_in[4];
  const float* proj_w = (const float*)d_in[5];
  const float* proj_b = (const float*)d_in[6];
  const int*   ridx   = (const int*)d_in[7];
  float* out = (float*)d_out;

  char* p = (char*)d_ws;
  auto carve = [&](size_t bytes) { char* r = p; p += (bytes + 255) & ~(size_t)255; return r; };
  unsigned short* xb   = (unsigned short*)carve((size_t)ROWS * DIMC * 2);
  unsigned short* wb   = (unsigned short*)carve((size_t)3 * DIMC * DIMC * 2);
  unsigned short* pb   = (unsigned short*)carve((size_t)DIMC * DIMC * 2);
  float*          Bias = (float*)carve((size_t)NH * NTOK * NTOK * 4);
  unsigned short* Q    = (unsigned short*)carve((size_t)BHN * NTOK * HD * 2);
  unsigned short* Kb   = (unsigned short*)carve((size_t)BHN * NTOK * HD * 2);
  unsigned short* Vt   = (unsigned short*)carve((size_t)BHN * HD * NPAD * 2);
  unsigned short* Abuf = xb;  // xb is dead after GEMM1; attn fully overwrites

  k_cvt<<<(ROWS * DIMC / 4 + 255) / 256, 256, 0, stream>>>(x, xb, ROWS * DIMC / 4);
  k_cvt<<<(3 * DIMC * DIMC / 4 + 255) / 256, 256, 0, stream>>>(qkv_w, wb, 3 * DIMC * DIMC / 4);
  k_cvt<<<(DIMC * DIMC / 4 + 255) / 256, 256, 0, stream>>>(proj_w, pb, DIMC * DIMC / 4);
  k_bias<<<(NH * NTOK * NTOK + 255) / 256, 256, 0, stream>>>(rtab, ridx, Bias);
  k_vtpad<<<(BHN * HD * (NPAD - NTOK) + 255) / 256, 256, 0, stream>>>(Vt);

  dim3 g1(99, 18);
  k_gemm<0><<<g1, 256, 0, stream>>>(xb, wb, q_bias, v_bias, Q, Kb, Vt, nullptr);

  k_attn<<<BHN, 256, 0, stream>>>(Q, Kb, Vt, Bias, Abuf);

  dim3 g2(99, 6);
  k_gemm<1><<<g2, 256, 0, stream>>>(Abuf, pb, proj_b, nullptr, nullptr, nullptr, nullptr, out);
}